// Round 1
// baseline (4178.368 us; speedup 1.0000x reference)
//
#include <hip/hip_runtime.h>

// ReservoirLayer: S0 = pad(x,[2048,4096]); 16x: S = leaky_relu(S @ W, 0.1)
// fp32-emulation via fp16 hi/lo split (fp16x3): acc = Sh@Wh + Sl@Wh + Sh@Wl.
// R3: depth-2 software pipeline (frags lead MFMAs by 1 iter, staging by 2).
// R4: MFMA shape 16x16x32 -> 32x32x16 (same f16 math, ~+11-25% pipe ceiling,
//     half the MFMA issue count). LDS layout k-half-major [kh][row][16f16]:
//     every ds_read_b128 covers a contiguous 1KB block -> conflict-free, no
//     swizzle; global_load_lds dst stays base + lane*16.

#define BATCH 2048
#define NDIM  4096
#define INDIM 512
#define BM 128
#define BN 128
#define BK 32

typedef _Float16 f16x8  __attribute__((ext_vector_type(8)));
typedef float    f32x16 __attribute__((ext_vector_type(16)));

__device__ __forceinline__ void async16(const void* gsrc, void* ldst) {
  const __attribute__((address_space(1))) unsigned int* g =
      (const __attribute__((address_space(1))) unsigned int*)gsrc;
  __attribute__((address_space(3))) unsigned int* l =
      (__attribute__((address_space(3))) unsigned int*)ldst;
  __builtin_amdgcn_global_load_lds(g, l, 16, 0, 0);
}

// ---------------- prep: split+pad x into S_hi/S_lo ----------------
__global__ void prep_x(const float* __restrict__ x,
                       _Float16* __restrict__ Sh, _Float16* __restrict__ Sl) {
  size_t i = (size_t)blockIdx.x * 256 + threadIdx.x;  // over BATCH*NDIM
  int b = (int)(i >> 12);
  int n = (int)(i & (NDIM - 1));
  float v = (n < INDIM) ? x[(size_t)b * INDIM + n] : 0.0f;
  _Float16 h = (_Float16)v;
  Sh[i] = h;
  Sl[i] = (_Float16)(v - (float)h);
}

// ---------------- prep: transpose + scale(256) + split W ----------------
__global__ void prep_w(const float* __restrict__ W,
                       _Float16* __restrict__ Wth, _Float16* __restrict__ Wtl) {
  __shared__ float tile[32][33];
  int k0 = blockIdx.y * 32, n0 = blockIdx.x * 32;
  int tx = threadIdx.x, ty = threadIdx.y;  // 32 x 8
  for (int r = 0; r < 4; r++) {
    int k = k0 + ty + r * 8;
    tile[ty + r * 8][tx] = W[(size_t)k * NDIM + n0 + tx];
  }
  __syncthreads();
  for (int r = 0; r < 4; r++) {
    int n = n0 + ty + r * 8;
    float v = tile[tx][ty + r * 8] * 256.0f;
    _Float16 h = (_Float16)v;
    Wth[(size_t)n * NDIM + k0 + tx] = h;
    Wtl[(size_t)n * NDIM + k0 + tx] = (_Float16)(v - (float)h);
  }
}

// read one frag set from LDS buffers b (compile-time 0/1 at all call sites)
#define READF(b, A, L, Bv, M)                          \
  do {                                                 \
    _Pragma("unroll") for (int i = 0; i < 2; i++)      \
    _Pragma("unroll") for (int s = 0; s < 2; s++) {    \
      A[i][s]  = *(const f16x8*)&sAh[b][oA[i][s]];     \
      L[i][s]  = *(const f16x8*)&sAl[b][oA[i][s]];     \
      Bv[i][s] = *(const f16x8*)&sBh[b][oB[i][s]];     \
      M[i][s]  = *(const f16x8*)&sBl[b][oB[i][s]];     \
    }                                                  \
  } while (0)

// term-major order: consecutive MFMAs hit different accs (4-apart dep chain)
#define MFMAS(A, L, Bv, M)                                                                   \
  do {                                                                                       \
    _Pragma("unroll") for (int s = 0; s < 2; s++) {                                          \
      _Pragma("unroll") for (int j = 0; j < 2; j++)                                          \
      _Pragma("unroll") for (int i = 0; i < 2; i++)                                          \
        acc[i][j] = __builtin_amdgcn_mfma_f32_32x32x16_f16(A[i][s], Bv[j][s], acc[i][j], 0, 0, 0); \
      _Pragma("unroll") for (int j = 0; j < 2; j++)                                          \
      _Pragma("unroll") for (int i = 0; i < 2; i++)                                          \
        acc[i][j] = __builtin_amdgcn_mfma_f32_32x32x16_f16(L[i][s], Bv[j][s], acc[i][j], 0, 0, 0); \
      _Pragma("unroll") for (int j = 0; j < 2; j++)                                          \
      _Pragma("unroll") for (int i = 0; i < 2; i++)                                          \
        acc[i][j] = __builtin_amdgcn_mfma_f32_32x32x16_f16(A[i][s], M[j][s], acc[i][j], 0, 0, 0); \
    }                                                                                        \
  } while (0)

// ---------------- one recurrence step ----------------
template <int MODE>
__global__ __launch_bounds__(256, 2) void step_kernel(
    const _Float16* __restrict__ Ah, const _Float16* __restrict__ Al,
    const _Float16* __restrict__ Bh, const _Float16* __restrict__ Bl,
    _Float16* __restrict__ Dh, _Float16* __restrict__ Dl,
    float* __restrict__ Dout, int k_len) {
  // k-half-major: [buf][kh*(R*16) + row*16 + e], R=BM/BN. 8 KB per array/buf.
  __shared__ __align__(16) _Float16 sAh[2][2 * BM * 16];
  __shared__ __align__(16) _Float16 sAl[2][2 * BM * 16];
  __shared__ __align__(16) _Float16 sBh[2][2 * BN * 16];
  __shared__ __align__(16) _Float16 sBl[2][2 * BN * 16];

  const int tid = threadIdx.x;
  const int lane = tid & 63;
  const int w = tid >> 6;
  const int wm = w >> 1, wn = w & 1;

  // XCD-aware swizzle: 8x8 block region per XCD (round-robin dispatch, id&7)
  int id = blockIdx.x;
  int xcd = id & 7, local = id >> 3;
  int lr = local & 7, lc = local >> 3;
  const int bm = ((xcd & 1) * 8 + lr) * BM;
  const int bn = ((xcd >> 1) * 8 + lc) * BN;

  const int r31 = lane & 31;   // 32x32 frag row/col
  const int kh = lane >> 5;    // k-half select within K=16 frag

  // loop-invariant LDS fragment element-offsets
  // frag(i, k-sub s): lane reads 8 f16 at [s-half][row][kh*8]
  int oA[2][2], oB[2][2];
#pragma unroll
  for (int i = 0; i < 2; i++)
#pragma unroll
    for (int s = 0; s < 2; s++) {
      oA[i][s] = s * (BM * 16) + (wm * 64 + i * 32 + r31) * 16 + kh * 8;
      oB[i][s] = s * (BN * 16) + (wn * 64 + i * 32 + r31) * 16 + kh * 8;
    }

  // staging: wave w stages rows [w*32, w*32+32), call q stages k-half q.
  // LDS dst = base(w,q) + lane*16B  (global_load_lds contiguity requirement)
  const int srow = w * 32 + (lane >> 1);
  const int ksub = (lane & 1) * 8;
  size_t gA[2], gB[2];
  int dOff[2];
#pragma unroll
  for (int q = 0; q < 2; q++) {
    gA[q] = (size_t)(bm + srow) * NDIM + q * 16 + ksub;
    gB[q] = (size_t)(bn + srow) * NDIM + q * 16 + ksub;
    dOff[q] = q * (BM * 16) + srow * 16 + ksub;
  }

  auto stage = [&](int kt, int b) {
#pragma unroll
    for (int q = 0; q < 2; q++) {
      async16(Ah + gA[q] + kt, &sAh[b][dOff[q]]);
      async16(Al + gA[q] + kt, &sAl[b][dOff[q]]);
      async16(Bh + gB[q] + kt, &sBh[b][dOff[q]]);
      async16(Bl + gB[q] + kt, &sBl[b][dOff[q]]);
    }
  };

  f32x16 acc[2][2];
#pragma unroll
  for (int i = 0; i < 2; i++)
#pragma unroll
    for (int j = 0; j < 2; j++)
#pragma unroll
      for (int e = 0; e < 16; e++) acc[i][j][e] = 0.0f;

  f16x8 a0[2][2], l0[2][2], b0[2][2], m0[2][2];  // frag set 0
  f16x8 a1[2][2], l1[2][2], b1[2][2], m1[2][2];  // frag set 1

  const int nk = k_len / BK;  // 16 or 128 (even)

  // prologue
  stage(0 * BK, 0);
  stage(1 * BK, 1);
  __syncthreads();               // tiles 0,1 staged (one-time drain)
  READF(0, a0, l0, b0, m0);
  __syncthreads();               // reads(0) drained -> buf0 reusable
  stage(2 * BK, 0);

  // main: READF(it) | MFMA(it-1) | sync | stage(it+2)
  int it = 1;
  for (; it + 1 < nk; it += 2) {
    READF(1, a1, l1, b1, m1);    // reads(it), it odd -> buf1
    MFMAS(a0, l0, b0, m0);       // MFMA(it-1)
    __syncthreads();
    if (it + 2 < nk) stage((it + 2) * BK, 1);

    READF(0, a0, l0, b0, m0);    // reads(it+1), even -> buf0
    MFMAS(a1, l1, b1, m1);       // MFMA(it)
    __syncthreads();
    if (it + 3 < nk) stage((it + 3) * BK, 0);
  }
  // tail: it == nk-1 (odd)
  READF(1, a1, l1, b1, m1);      // reads(nk-1)
  MFMAS(a0, l0, b0, m0);         // MFMA(nk-2)
  MFMAS(a1, l1, b1, m1);         // MFMA(nk-1)

  // ---- epilogue: undo 256x W-scale, leaky relu, write next state / output
  // 32x32 C/D layout: col = lane&31, row = (reg&3) + 8*(reg>>2) + 4*(lane>>5)
  const float inv = 1.0f / 256.0f;
#pragma unroll
  for (int i = 0; i < 2; i++) {
#pragma unroll
    for (int j = 0; j < 2; j++) {
#pragma unroll
      for (int e = 0; e < 16; e++) {
        int r = bm + wm * 64 + i * 32 + (e & 3) + 8 * (e >> 2) + 4 * kh;
        int c = bn + wn * 64 + j * 32 + r31;
        float g = acc[i][j][e] * inv;
        float s = (g > 0.0f) ? g : 0.1f * g;
        if (MODE == 0) {
          _Float16 h = (_Float16)s;
          Dh[(size_t)r * NDIM + c] = h;
          Dl[(size_t)r * NDIM + c] = (_Float16)(s - (float)h);
        } else {
          Dout[(size_t)r * NDIM + c] = s;
        }
      }
    }
  }
}

extern "C" void kernel_launch(void* const* d_in, const int* in_sizes, int n_in,
                              void* d_out, int out_size, void* d_ws, size_t ws_size,
                              hipStream_t stream) {
  const float* x = (const float*)d_in[0];  // [2048, 512]
  const float* W = (const float*)d_in[1];  // [4096, 4096]
  float* out = (float*)d_out;              // [2048, 4096]
  char* ws = (char*)d_ws;

  const size_t WT_BYTES = (size_t)NDIM * NDIM * 2;  // 32 MB each
  const size_t S_BYTES = (size_t)BATCH * NDIM * 2;  // 16 MB each
  _Float16* Wth = (_Float16*)ws;
  _Float16* Wtl = (_Float16*)(ws + WT_BYTES);
  _Float16* SAh = (_Float16*)(ws + 2 * WT_BYTES);
  _Float16* SAl = (_Float16*)(ws + 2 * WT_BYTES + S_BYTES);
  _Float16* SBh = (_Float16*)(ws + 2 * WT_BYTES + 2 * S_BYTES);
  _Float16* SBl = (_Float16*)(ws + 2 * WT_BYTES + 3 * S_BYTES);

  prep_x<<<(BATCH * NDIM) / 256, 256, 0, stream>>>(x, SAh, SAl);
  prep_w<<<dim3(NDIM / 32, NDIM / 32), dim3(32, 8), 0, stream>>>(W, Wth, Wtl);

  dim3 grid((NDIM / BN) * (BATCH / BM));  // 512 linear, swizzled in-kernel
  for (int t = 1; t <= 16; t++) {
    const _Float16* ah = (t & 1) ? SAh : SBh;
    const _Float16* al = (t & 1) ? SAl : SBl;
    _Float16* dh = (t & 1) ? SBh : SAh;
    _Float16* dl = (t & 1) ? SBl : SAl;
    int klen = (t == 1) ? INDIM : NDIM;
    if (t < 16)
      step_kernel<0><<<grid, 256, 0, stream>>>(ah, al, Wth, Wtl, dh, dl, nullptr, klen);
    else
      step_kernel<1><<<grid, 256, 0, stream>>>(ah, al, Wth, Wtl, nullptr, nullptr, out, klen);
  }
}

// Round 2
// 2658.194 us; speedup vs baseline: 1.5719x; 1.5719x over previous
//
#include <hip/hip_runtime.h>

// ReservoirLayer: S0 = pad(x,[2048,4096]); 16x: S = leaky_relu(S @ W, 0.1)
// fp32-emulation via fp16 hi/lo split (fp16x3): acc = Sh@Wh + Sl@Wh + Sh@Wl.
// R3: depth-2 software pipeline (frags lead MFMAs by 1 iter, staging by 2).
// R5: 32x32x16 MFMA (24 fat MFMAs/K-tile instead of 48) on top of R3's
//     EXACT LDS layout + staging (empirically conflict-free; R4's row-major
//     [row][16] layout was a 4-way bank conflict per 8-lane phase -> 16.7M
//     conflict cycles). Frag reads pick chunk (s*2+kh) ^ ((row>>1)&3).

#define BATCH 2048
#define NDIM  4096
#define INDIM 512
#define BM 128
#define BN 128
#define BK 32

typedef _Float16 f16x8  __attribute__((ext_vector_type(8)));
typedef float    f32x16 __attribute__((ext_vector_type(16)));

__device__ __forceinline__ void async16(const void* gsrc, void* ldst) {
  const __attribute__((address_space(1))) unsigned int* g =
      (const __attribute__((address_space(1))) unsigned int*)gsrc;
  __attribute__((address_space(3))) unsigned int* l =
      (__attribute__((address_space(3))) unsigned int*)ldst;
  __builtin_amdgcn_global_load_lds(g, l, 16, 0, 0);
}

// ---------------- prep: split+pad x into S_hi/S_lo ----------------
__global__ void prep_x(const float* __restrict__ x,
                       _Float16* __restrict__ Sh, _Float16* __restrict__ Sl) {
  size_t i = (size_t)blockIdx.x * 256 + threadIdx.x;  // over BATCH*NDIM
  int b = (int)(i >> 12);
  int n = (int)(i & (NDIM - 1));
  float v = (n < INDIM) ? x[(size_t)b * INDIM + n] : 0.0f;
  _Float16 h = (_Float16)v;
  Sh[i] = h;
  Sl[i] = (_Float16)(v - (float)h);
}

// ---------------- prep: transpose + scale(256) + split W ----------------
__global__ void prep_w(const float* __restrict__ W,
                       _Float16* __restrict__ Wth, _Float16* __restrict__ Wtl) {
  __shared__ float tile[32][33];
  int k0 = blockIdx.y * 32, n0 = blockIdx.x * 32;
  int tx = threadIdx.x, ty = threadIdx.y;  // 32 x 8
  for (int r = 0; r < 4; r++) {
    int k = k0 + ty + r * 8;
    tile[ty + r * 8][tx] = W[(size_t)k * NDIM + n0 + tx];
  }
  __syncthreads();
  for (int r = 0; r < 4; r++) {
    int n = n0 + ty + r * 8;
    float v = tile[tx][ty + r * 8] * 256.0f;
    _Float16 h = (_Float16)v;
    Wth[(size_t)n * NDIM + k0 + tx] = h;
    Wtl[(size_t)n * NDIM + k0 + tx] = (_Float16)(v - (float)h);
  }
}

// read one frag set from LDS buffers b (compile-time 0/1 at all call sites)
#define READF(b, A, L, Bv, M)                          \
  do {                                                 \
    _Pragma("unroll") for (int i = 0; i < 2; i++)      \
    _Pragma("unroll") for (int s = 0; s < 2; s++) {    \
      A[i][s]  = *(const f16x8*)&sAh[b][oA[i][s]];     \
      L[i][s]  = *(const f16x8*)&sAl[b][oA[i][s]];     \
      Bv[i][s] = *(const f16x8*)&sBh[b][oB[i][s]];     \
      M[i][s]  = *(const f16x8*)&sBl[b][oB[i][s]];     \
    }                                                  \
  } while (0)

// term-major order: consecutive MFMAs hit different accs (4-apart dep chain)
#define MFMAS(A, L, Bv, M)                                                                   \
  do {                                                                                       \
    _Pragma("unroll") for (int s = 0; s < 2; s++) {                                          \
      _Pragma("unroll") for (int j = 0; j < 2; j++)                                          \
      _Pragma("unroll") for (int i = 0; i < 2; i++)                                          \
        acc[i][j] = __builtin_amdgcn_mfma_f32_32x32x16_f16(A[i][s], Bv[j][s], acc[i][j], 0, 0, 0); \
      _Pragma("unroll") for (int j = 0; j < 2; j++)                                          \
      _Pragma("unroll") for (int i = 0; i < 2; i++)                                          \
        acc[i][j] = __builtin_amdgcn_mfma_f32_32x32x16_f16(L[i][s], Bv[j][s], acc[i][j], 0, 0, 0); \
      _Pragma("unroll") for (int j = 0; j < 2; j++)                                          \
      _Pragma("unroll") for (int i = 0; i < 2; i++)                                          \
        acc[i][j] = __builtin_amdgcn_mfma_f32_32x32x16_f16(A[i][s], M[j][s], acc[i][j], 0, 0, 0); \
    }                                                                                        \
  } while (0)

// ---------------- one recurrence step ----------------
template <int MODE>
__global__ __launch_bounds__(256, 2) void step_kernel(
    const _Float16* __restrict__ Ah, const _Float16* __restrict__ Al,
    const _Float16* __restrict__ Bh, const _Float16* __restrict__ Bl,
    _Float16* __restrict__ Dh, _Float16* __restrict__ Dl,
    float* __restrict__ Dout, int k_len) {
  // R3 layout: [row][BK], k-chunks XOR-swizzled per row (conflict-free, proven)
  __shared__ _Float16 sAh[2][BM * BK];
  __shared__ _Float16 sAl[2][BM * BK];
  __shared__ _Float16 sBh[2][BN * BK];
  __shared__ _Float16 sBl[2][BN * BK];

  const int tid = threadIdx.x;
  const int lane = tid & 63;
  const int w = tid >> 6;
  const int wm = w >> 1, wn = w & 1;

  // XCD-aware swizzle: 8x8 block region per XCD (round-robin dispatch, id&7)
  int id = blockIdx.x;
  int xcd = id & 7, local = id >> 3;
  int lr = local & 7, lc = local >> 3;
  const int bm = ((xcd & 1) * 8 + lr) * BM;
  const int bn = ((xcd >> 1) * 8 + lc) * BN;

  const int sr = lane >> 2, cl = lane & 3;
  const int r31 = lane & 31;   // 32x32 frag row/col
  const int kh = lane >> 5;    // which 8-elem k-chunk within the K=16 sub-frag

  // loop-invariant LDS fragment element-offsets.
  // Global k-chunk wanted for sub-frag s is (s*2+kh); stored at LDS chunk
  // (s*2+kh) ^ ((row>>1)&3)  (inverse of the staging swizzle, an involution).
  int oA[2][2], oB[2][2];
#pragma unroll
  for (int i = 0; i < 2; i++) {
    int rA = wm * 64 + i * 32 + r31;
    int rB = wn * 64 + i * 32 + r31;
#pragma unroll
    for (int s = 0; s < 2; s++) {
      oA[i][s] = rA * BK + ((s * 2 + kh) ^ ((rA >> 1) & 3)) * 8;
      oB[i][s] = rB * BK + ((s * 2 + kh) ^ ((rB >> 1) & 3)) * 8;
    }
  }

  // staging (R3, unchanged): 4 lanes/row, 64 B contiguous per row, LDS dst
  // lane-linear (global_load_lds requirement), k-chunks pre-swizzled on the
  // global side.
  int r0 = w * 32 + sr, r1 = r0 + 16;
  int cg0 = cl ^ ((r0 >> 1) & 3);
  int cg1 = cl ^ ((r1 >> 1) & 3);
  const size_t gA0 = (size_t)(bm + r0) * NDIM + cg0 * 8;
  const size_t gA1 = (size_t)(bm + r1) * NDIM + cg1 * 8;
  const size_t gB0 = (size_t)(bn + r0) * NDIM + cg0 * 8;
  const size_t gB1 = (size_t)(bn + r1) * NDIM + cg1 * 8;
  const int lo0 = r0 * BK + cl * 8;
  const int lo1 = r1 * BK + cl * 8;

  auto stage = [&](int kt, int b) {
    async16(Ah + gA0 + kt, &sAh[b][lo0]);
    async16(Ah + gA1 + kt, &sAh[b][lo1]);
    async16(Al + gA0 + kt, &sAl[b][lo0]);
    async16(Al + gA1 + kt, &sAl[b][lo1]);
    async16(Bh + gB0 + kt, &sBh[b][lo0]);
    async16(Bh + gB1 + kt, &sBh[b][lo1]);
    async16(Bl + gB0 + kt, &sBl[b][lo0]);
    async16(Bl + gB1 + kt, &sBl[b][lo1]);
  };

  f32x16 acc[2][2];
#pragma unroll
  for (int i = 0; i < 2; i++)
#pragma unroll
    for (int j = 0; j < 2; j++)
#pragma unroll
      for (int e = 0; e < 16; e++) acc[i][j][e] = 0.0f;

  f16x8 a0[2][2], l0[2][2], b0[2][2], m0[2][2];  // frag set 0
  f16x8 a1[2][2], l1[2][2], b1[2][2], m1[2][2];  // frag set 1

  const int nk = k_len / BK;  // 16 or 128 (even)

  // prologue
  stage(0 * BK, 0);
  stage(1 * BK, 1);
  __syncthreads();               // tiles 0,1 staged (one-time drain)
  READF(0, a0, l0, b0, m0);
  __syncthreads();               // reads(0) drained -> buf0 reusable
  stage(2 * BK, 0);

  // main: READF(it) | MFMA(it-1) | sync | stage(it+2)
  int it = 1;
  for (; it + 1 < nk; it += 2) {
    READF(1, a1, l1, b1, m1);    // reads(it), it odd -> buf1
    MFMAS(a0, l0, b0, m0);       // MFMA(it-1)
    __syncthreads();
    if (it + 2 < nk) stage((it + 2) * BK, 1);

    READF(0, a0, l0, b0, m0);    // reads(it+1), even -> buf0
    MFMAS(a1, l1, b1, m1);       // MFMA(it)
    __syncthreads();
    if (it + 3 < nk) stage((it + 3) * BK, 0);
  }
  // tail: it == nk-1 (odd)
  READF(1, a1, l1, b1, m1);      // reads(nk-1)
  MFMAS(a0, l0, b0, m0);         // MFMA(nk-2)
  MFMAS(a1, l1, b1, m1);         // MFMA(nk-1)

  // ---- epilogue: undo 256x W-scale, leaky relu, write next state / output
  // 32x32 C/D layout: col = lane&31, row = (reg&3) + 8*(reg>>2) + 4*(lane>>5)
  const float inv = 1.0f / 256.0f;
#pragma unroll
  for (int i = 0; i < 2; i++) {
#pragma unroll
    for (int j = 0; j < 2; j++) {
#pragma unroll
      for (int e = 0; e < 16; e++) {
        int r = bm + wm * 64 + i * 32 + (e & 3) + 8 * (e >> 2) + 4 * kh;
        int c = bn + wn * 64 + j * 32 + r31;
        float g = acc[i][j][e] * inv;
        float s = (g > 0.0f) ? g : 0.1f * g;
        if (MODE == 0) {
          _Float16 h = (_Float16)s;
          Dh[(size_t)r * NDIM + c] = h;
          Dl[(size_t)r * NDIM + c] = (_Float16)(s - (float)h);
        } else {
          Dout[(size_t)r * NDIM + c] = s;
        }
      }
    }
  }
}

extern "C" void kernel_launch(void* const* d_in, const int* in_sizes, int n_in,
                              void* d_out, int out_size, void* d_ws, size_t ws_size,
                              hipStream_t stream) {
  const float* x = (const float*)d_in[0];  // [2048, 512]
  const float* W = (const float*)d_in[1];  // [4096, 4096]
  float* out = (float*)d_out;              // [2048, 4096]
  char* ws = (char*)d_ws;

  const size_t WT_BYTES = (size_t)NDIM * NDIM * 2;  // 32 MB each
  const size_t S_BYTES = (size_t)BATCH * NDIM * 2;  // 16 MB each
  _Float16* Wth = (_Float16*)ws;
  _Float16* Wtl = (_Float16*)(ws + WT_BYTES);
  _Float16* SAh = (_Float16*)(ws + 2 * WT_BYTES);
  _Float16* SAl = (_Float16*)(ws + 2 * WT_BYTES + S_BYTES);
  _Float16* SBh = (_Float16*)(ws + 2 * WT_BYTES + 2 * S_BYTES);
  _Float16* SBl = (_Float16*)(ws + 2 * WT_BYTES + 3 * S_BYTES);

  prep_x<<<(BATCH * NDIM) / 256, 256, 0, stream>>>(x, SAh, SAl);
  prep_w<<<dim3(NDIM / 32, NDIM / 32), dim3(32, 8), 0, stream>>>(W, Wth, Wtl);

  dim3 grid((NDIM / BN) * (BATCH / BM));  // 512 linear, swizzled in-kernel
  for (int t = 1; t <= 16; t++) {
    const _Float16* ah = (t & 1) ? SAh : SBh;
    const _Float16* al = (t & 1) ? SAl : SBl;
    _Float16* dh = (t & 1) ? SBh : SAh;
    _Float16* dl = (t & 1) ? SBl : SAl;
    int klen = (t == 1) ? INDIM : NDIM;
    if (t < 16)
      step_kernel<0><<<grid, 256, 0, stream>>>(ah, al, Wth, Wtl, dh, dl, nullptr, klen);
    else
      step_kernel<1><<<grid, 256, 0, stream>>>(ah, al, Wth, Wtl, nullptr, nullptr, out, klen);
  }
}

// Round 3
// 2622.508 us; speedup vs baseline: 1.5933x; 1.0136x over previous
//
#include <hip/hip_runtime.h>

// ReservoirLayer: S0 = pad(x,[2048,4096]); 16x: S = leaky_relu(S @ W, 0.1)
// fp32-emulation via fp16 hi/lo split (fp16x3): acc = Sh@Wh + Sl@Wh + Sh@Wl.
// R3: depth-2 software pipeline (frags lead MFMAs by 1 iter, staging by 2).
// R5: 32x32x16 MFMA (24 fat MFMAs/K-tile instead of 48).
// R6: fix the 4-cyc/read bank conflict R5 introduced. Evidence: conflicts =
//     exactly 4 x (#ds_read_b128). Model: DS pipe co-processes lane quads
//     {l,l+16,l+32,l+48}; in the 32x32 frag map these are rows {r,r+16} x
//     kh{0,1}, and ((r+16)>>1)&3 == (r>>1)&3, so the old XOR mask gave the
//     quad only 2 distinct chunks -> 4 words/bank. Fix: fold row bit 4 into
//     the mask: m(r) = ((r>>1)&3) ^ (((r>>4)&1)<<1)  -> quad spans all 4
//     chunks. Applied identically to staging (global-side) and reads.

#define BATCH 2048
#define NDIM  4096
#define INDIM 512
#define BM 128
#define BN 128
#define BK 32

typedef _Float16 f16x8  __attribute__((ext_vector_type(8)));
typedef float    f32x16 __attribute__((ext_vector_type(16)));

__device__ __forceinline__ void async16(const void* gsrc, void* ldst) {
  const __attribute__((address_space(1))) unsigned int* g =
      (const __attribute__((address_space(1))) unsigned int*)gsrc;
  __attribute__((address_space(3))) unsigned int* l =
      (__attribute__((address_space(3))) unsigned int*)ldst;
  __builtin_amdgcn_global_load_lds(g, l, 16, 0, 0);
}

__device__ __forceinline__ int swzm(int r) {  // chunk-swizzle mask per row
  return ((r >> 1) & 3) ^ (((r >> 4) & 1) << 1);
}

// ---------------- prep: split+pad x into S_hi/S_lo ----------------
__global__ void prep_x(const float* __restrict__ x,
                       _Float16* __restrict__ Sh, _Float16* __restrict__ Sl) {
  size_t i = (size_t)blockIdx.x * 256 + threadIdx.x;  // over BATCH*NDIM
  int b = (int)(i >> 12);
  int n = (int)(i & (NDIM - 1));
  float v = (n < INDIM) ? x[(size_t)b * INDIM + n] : 0.0f;
  _Float16 h = (_Float16)v;
  Sh[i] = h;
  Sl[i] = (_Float16)(v - (float)h);
}

// ---------------- prep: transpose + scale(256) + split W ----------------
__global__ void prep_w(const float* __restrict__ W,
                       _Float16* __restrict__ Wth, _Float16* __restrict__ Wtl) {
  __shared__ float tile[32][33];
  int k0 = blockIdx.y * 32, n0 = blockIdx.x * 32;
  int tx = threadIdx.x, ty = threadIdx.y;  // 32 x 8
  for (int r = 0; r < 4; r++) {
    int k = k0 + ty + r * 8;
    tile[ty + r * 8][tx] = W[(size_t)k * NDIM + n0 + tx];
  }
  __syncthreads();
  for (int r = 0; r < 4; r++) {
    int n = n0 + ty + r * 8;
    float v = tile[tx][ty + r * 8] * 256.0f;
    _Float16 h = (_Float16)v;
    Wth[(size_t)n * NDIM + k0 + tx] = h;
    Wtl[(size_t)n * NDIM + k0 + tx] = (_Float16)(v - (float)h);
  }
}

// read one frag set from LDS buffers b (compile-time 0/1 at all call sites)
#define READF(b, A, L, Bv, M)                          \
  do {                                                 \
    _Pragma("unroll") for (int i = 0; i < 2; i++)      \
    _Pragma("unroll") for (int s = 0; s < 2; s++) {    \
      A[i][s]  = *(const f16x8*)&sAh[b][oA[i][s]];     \
      L[i][s]  = *(const f16x8*)&sAl[b][oA[i][s]];     \
      Bv[i][s] = *(const f16x8*)&sBh[b][oB[i][s]];     \
      M[i][s]  = *(const f16x8*)&sBl[b][oB[i][s]];     \
    }                                                  \
  } while (0)

// term-major order: consecutive MFMAs hit different accs (4-apart dep chain)
#define MFMAS(A, L, Bv, M)                                                                   \
  do {                                                                                       \
    _Pragma("unroll") for (int s = 0; s < 2; s++) {                                          \
      _Pragma("unroll") for (int j = 0; j < 2; j++)                                          \
      _Pragma("unroll") for (int i = 0; i < 2; i++)                                          \
        acc[i][j] = __builtin_amdgcn_mfma_f32_32x32x16_f16(A[i][s], Bv[j][s], acc[i][j], 0, 0, 0); \
      _Pragma("unroll") for (int j = 0; j < 2; j++)                                          \
      _Pragma("unroll") for (int i = 0; i < 2; i++)                                          \
        acc[i][j] = __builtin_amdgcn_mfma_f32_32x32x16_f16(L[i][s], Bv[j][s], acc[i][j], 0, 0, 0); \
      _Pragma("unroll") for (int j = 0; j < 2; j++)                                          \
      _Pragma("unroll") for (int i = 0; i < 2; i++)                                          \
        acc[i][j] = __builtin_amdgcn_mfma_f32_32x32x16_f16(A[i][s], M[j][s], acc[i][j], 0, 0, 0); \
    }                                                                                        \
  } while (0)

// ---------------- one recurrence step ----------------
template <int MODE>
__global__ __launch_bounds__(256, 2) void step_kernel(
    const _Float16* __restrict__ Ah, const _Float16* __restrict__ Al,
    const _Float16* __restrict__ Bh, const _Float16* __restrict__ Bl,
    _Float16* __restrict__ Dh, _Float16* __restrict__ Dl,
    float* __restrict__ Dout, int k_len) {
  // [row][BK] layout, per-row chunk permutation swzm(r) (XOR involution)
  __shared__ _Float16 sAh[2][BM * BK];
  __shared__ _Float16 sAl[2][BM * BK];
  __shared__ _Float16 sBh[2][BN * BK];
  __shared__ _Float16 sBl[2][BN * BK];

  const int tid = threadIdx.x;
  const int lane = tid & 63;
  const int w = tid >> 6;
  const int wm = w >> 1, wn = w & 1;

  // XCD-aware swizzle: 8x8 block region per XCD (round-robin dispatch, id&7)
  int id = blockIdx.x;
  int xcd = id & 7, local = id >> 3;
  int lr = local & 7, lc = local >> 3;
  const int bm = ((xcd & 1) * 8 + lr) * BM;
  const int bn = ((xcd >> 1) * 8 + lc) * BN;

  const int sr = lane >> 2, cl = lane & 3;
  const int r31 = lane & 31;   // 32x32 frag row/col
  const int kh = lane >> 5;    // which 8-elem k-chunk within the K=16 sub-frag

  // loop-invariant LDS fragment element-offsets.
  // Global k-chunk wanted for sub-frag s is (s*2+kh); stored at LDS chunk
  // (s*2+kh) ^ swzm(row).
  int oA[2][2], oB[2][2];
#pragma unroll
  for (int i = 0; i < 2; i++) {
    int rA = wm * 64 + i * 32 + r31;
    int rB = wn * 64 + i * 32 + r31;
#pragma unroll
    for (int s = 0; s < 2; s++) {
      oA[i][s] = rA * BK + ((s * 2 + kh) ^ swzm(rA)) * 8;
      oB[i][s] = rB * BK + ((s * 2 + kh) ^ swzm(rB)) * 8;
    }
  }

  // staging: 4 lanes/row, 64 B contiguous per row, LDS dst lane-linear
  // (global_load_lds requirement), k-chunks pre-swizzled on the global side.
  int r0 = w * 32 + sr, r1 = r0 + 16;
  int cg0 = cl ^ swzm(r0);
  int cg1 = cl ^ swzm(r1);
  const size_t gA0 = (size_t)(bm + r0) * NDIM + cg0 * 8;
  const size_t gA1 = (size_t)(bm + r1) * NDIM + cg1 * 8;
  const size_t gB0 = (size_t)(bn + r0) * NDIM + cg0 * 8;
  const size_t gB1 = (size_t)(bn + r1) * NDIM + cg1 * 8;
  const int lo0 = r0 * BK + cl * 8;
  const int lo1 = r1 * BK + cl * 8;

  auto stage = [&](int kt, int b) {
    async16(Ah + gA0 + kt, &sAh[b][lo0]);
    async16(Ah + gA1 + kt, &sAh[b][lo1]);
    async16(Al + gA0 + kt, &sAl[b][lo0]);
    async16(Al + gA1 + kt, &sAl[b][lo1]);
    async16(Bh + gB0 + kt, &sBh[b][lo0]);
    async16(Bh + gB1 + kt, &sBh[b][lo1]);
    async16(Bl + gB0 + kt, &sBl[b][lo0]);
    async16(Bl + gB1 + kt, &sBl[b][lo1]);
  };

  f32x16 acc[2][2];
#pragma unroll
  for (int i = 0; i < 2; i++)
#pragma unroll
    for (int j = 0; j < 2; j++)
#pragma unroll
      for (int e = 0; e < 16; e++) acc[i][j][e] = 0.0f;

  f16x8 a0[2][2], l0[2][2], b0[2][2], m0[2][2];  // frag set 0
  f16x8 a1[2][2], l1[2][2], b1[2][2], m1[2][2];  // frag set 1

  const int nk = k_len / BK;  // 16 or 128 (even)

  // prologue
  stage(0 * BK, 0);
  stage(1 * BK, 1);
  __syncthreads();               // tiles 0,1 staged (one-time drain)
  READF(0, a0, l0, b0, m0);
  __syncthreads();               // reads(0) drained -> buf0 reusable
  stage(2 * BK, 0);

  // main: READF(it) | MFMA(it-1) | sync | stage(it+2)
  int it = 1;
  for (; it + 1 < nk; it += 2) {
    READF(1, a1, l1, b1, m1);    // reads(it), it odd -> buf1
    MFMAS(a0, l0, b0, m0);       // MFMA(it-1)
    __syncthreads();
    if (it + 2 < nk) stage((it + 2) * BK, 1);

    READF(0, a0, l0, b0, m0);    // reads(it+1), even -> buf0
    MFMAS(a1, l1, b1, m1);       // MFMA(it)
    __syncthreads();
    if (it + 3 < nk) stage((it + 3) * BK, 0);
  }
  // tail: it == nk-1 (odd)
  READF(1, a1, l1, b1, m1);      // reads(nk-1)
  MFMAS(a0, l0, b0, m0);         // MFMA(nk-2)
  MFMAS(a1, l1, b1, m1);         // MFMA(nk-1)

  // ---- epilogue: undo 256x W-scale, leaky relu, write next state / output
  // 32x32 C/D layout: col = lane&31, row = (reg&3) + 8*(reg>>2) + 4*(lane>>5)
  const float inv = 1.0f / 256.0f;
#pragma unroll
  for (int i = 0; i < 2; i++) {
#pragma unroll
    for (int j = 0; j < 2; j++) {
#pragma unroll
      for (int e = 0; e < 16; e++) {
        int r = bm + wm * 64 + i * 32 + (e & 3) + 8 * (e >> 2) + 4 * kh;
        int c = bn + wn * 64 + j * 32 + r31;
        float g = acc[i][j][e] * inv;
        float s = (g > 0.0f) ? g : 0.1f * g;
        if (MODE == 0) {
          _Float16 h = (_Float16)s;
          Dh[(size_t)r * NDIM + c] = h;
          Dl[(size_t)r * NDIM + c] = (_Float16)(s - (float)h);
        } else {
          Dout[(size_t)r * NDIM + c] = s;
        }
      }
    }
  }
}

extern "C" void kernel_launch(void* const* d_in, const int* in_sizes, int n_in,
                              void* d_out, int out_size, void* d_ws, size_t ws_size,
                              hipStream_t stream) {
  const float* x = (const float*)d_in[0];  // [2048, 512]
  const float* W = (const float*)d_in[1];  // [4096, 4096]
  float* out = (float*)d_out;              // [2048, 4096]
  char* ws = (char*)d_ws;

  const size_t WT_BYTES = (size_t)NDIM * NDIM * 2;  // 32 MB each
  const size_t S_BYTES = (size_t)BATCH * NDIM * 2;  // 16 MB each
  _Float16* Wth = (_Float16*)ws;
  _Float16* Wtl = (_Float16*)(ws + WT_BYTES);
  _Float16* SAh = (_Float16*)(ws + 2 * WT_BYTES);
  _Float16* SAl = (_Float16*)(ws + 2 * WT_BYTES + S_BYTES);
  _Float16* SBh = (_Float16*)(ws + 2 * WT_BYTES + 2 * S_BYTES);
  _Float16* SBl = (_Float16*)(ws + 2 * WT_BYTES + 3 * S_BYTES);

  prep_x<<<(BATCH * NDIM) / 256, 256, 0, stream>>>(x, SAh, SAl);
  prep_w<<<dim3(NDIM / 32, NDIM / 32), dim3(32, 8), 0, stream>>>(W, Wth, Wtl);

  dim3 grid((NDIM / BN) * (BATCH / BM));  // 512 linear, swizzled in-kernel
  for (int t = 1; t <= 16; t++) {
    const _Float16* ah = (t & 1) ? SAh : SBh;
    const _Float16* al = (t & 1) ? SAl : SBl;
    _Float16* dh = (t & 1) ? SBh : SAh;
    _Float16* dl = (t & 1) ? SBl : SAl;
    int klen = (t == 1) ? INDIM : NDIM;
    if (t < 16)
      step_kernel<0><<<grid, 256, 0, stream>>>(ah, al, Wth, Wtl, dh, dl, nullptr, klen);
    else
      step_kernel<1><<<grid, 256, 0, stream>>>(ah, al, Wth, Wtl, nullptr, nullptr, out, klen);
  }
}